// Round 1
// baseline (2186.380 us; speedup 1.0000x reference)
//
#include <hip/hip_runtime.h>
#include <math.h>

#define N_NODES 100000
#define F 32

// ---------------- degree / normalization ----------------
__global__ void deg_kernel(const int* __restrict__ col, float* __restrict__ deg, int E) {
    int i = blockIdx.x * blockDim.x + threadIdx.x;
    if (i < E) atomicAdd(&deg[col[i]], 1.0f);
}

__global__ void dis_kernel(float* __restrict__ deg, int n) {
    int i = blockIdx.x * blockDim.x + threadIdx.x;
    if (i < n) {
        float d = deg[i];
        deg[i] = (d > 0.0f) ? rsqrtf(d) : 0.0f;   // d>=1 when >0, so max(d,1)==d
    }
}

// ---------------- layer 1 transform: t = x @ W1 (x is N x 5) ----------------
__global__ void transform1_kernel(const float* __restrict__ x, const float* __restrict__ W,
                                  float* __restrict__ t, int n) {
    __shared__ float Ws[5 * F];
    int tid = threadIdx.x;
    if (tid < 5 * F) Ws[tid] = W[tid];
    __syncthreads();
    int gid = blockIdx.x * blockDim.x + tid;
    int node = gid >> 5;
    int f = gid & 31;
    if (node >= n) return;
    float acc = 0.0f;
#pragma unroll
    for (int k = 0; k < 5; k++) acc += x[node * 5 + k] * Ws[k * F + f];
    t[(size_t)node * F + f] = acc;
}

// ---------------- fused relu(h + b) @ W  (h is N x 32) ----------------
__global__ void transform_relu_kernel(const float* __restrict__ h, const float* __restrict__ b,
                                      const float* __restrict__ W, float* __restrict__ t, int n) {
    __shared__ float Ws[F * F];
    __shared__ float hs[256];
    int tid = threadIdx.x;
    for (int i = tid; i < F * F; i += 256) Ws[i] = W[i];
    int node = blockIdx.x * 8 + (tid >> 5);
    int f = tid & 31;
    float hv = 0.0f;
    if (node < n) hv = h[(size_t)node * F + f] + b[f];
    hs[tid] = hv > 0.0f ? hv : 0.0f;
    __syncthreads();
    if (node >= n) return;
    const float* hrow = &hs[(tid >> 5) << 5];
    float acc = 0.0f;
#pragma unroll
    for (int k = 0; k < F; k++) acc += hrow[k] * Ws[k * F + f];
    t[(size_t)node * F + f] = acc;
}

// ---------------- edge scatter: out[col] += dis[row]*dis[col] * t[row] ----------------
// 8 threads per edge, each handles a float4 feature group.
__global__ void scatter_kernel(const float* __restrict__ t, const int* __restrict__ row,
                               const int* __restrict__ col, const float* __restrict__ dis,
                               float* __restrict__ out, int E) {
    long gid = (long)blockIdx.x * blockDim.x + threadIdx.x;
    int e = (int)(gid >> 3);
    if (e >= E) return;
    int fg = ((int)gid & 7) << 2;
    int r = row[e], c = col[e];
    float nrm = dis[r] * dis[c];
    if (nrm == 0.0f) return;
    float4 v = *(const float4*)(t + (size_t)r * F + fg);
    float* o = out + (size_t)c * F + fg;
    atomicAdd(o + 0, v.x * nrm);
    atomicAdd(o + 1, v.y * nrm);
    atomicAdd(o + 2, v.z * nrm);
    atomicAdd(o + 3, v.w * nrm);
}

// ---------------- heads: distance/attention per node + block argmax partials ----------------
__global__ void heads_kernel(const float* __restrict__ h, const float* __restrict__ b3,
                             const float* __restrict__ Wd, const float* __restrict__ bd,
                             const float* __restrict__ Wa, const float* __restrict__ ba,
                             float* __restrict__ out, float* __restrict__ pmax,
                             int* __restrict__ pidx, int n) {
    int tid = threadIdx.x;
    int node = blockIdx.x * blockDim.x + tid;
    float att = -INFINITY;
    int myidx = 0x7fffffff;
    if (node < n) {
        float dacc = 0.0f, aacc = 0.0f;
#pragma unroll
        for (int k = 0; k < F; k++) {
            float hv = h[(size_t)node * F + k] + b3[k];
            hv = hv > 0.0f ? hv : 0.0f;
            dacc += hv * Wd[k];
            aacc += hv * Wa[k];
        }
        dacc += bd[0];
        aacc += ba[0];
        out[node] = dacc;
        out[N_NODES + node] = aacc;
        att = aacc;
        myidx = node;
    }
    __shared__ float smax[256];
    __shared__ int sidx[256];
    smax[tid] = att;
    sidx[tid] = myidx;
    __syncthreads();
    for (int s = 128; s > 0; s >>= 1) {
        if (tid < s) {
            float v2 = smax[tid + s];
            int i2 = sidx[tid + s];
            if (v2 > smax[tid] || (v2 == smax[tid] && i2 < sidx[tid])) {
                smax[tid] = v2;
                sidx[tid] = i2;
            }
        }
        __syncthreads();
    }
    if (tid == 0) {
        pmax[blockIdx.x] = smax[0];
        pidx[blockIdx.x] = sidx[0];
    }
}

// ---------------- final: reduce partials, compute target head outputs ----------------
__global__ void final_kernel(const float* __restrict__ pmax, const int* __restrict__ pidx,
                             int nblocks, const float* __restrict__ h, const float* __restrict__ b3,
                             const float* __restrict__ Wt, const float* __restrict__ bt,
                             const float* __restrict__ Wact, const float* __restrict__ bact,
                             float* __restrict__ out) {
    __shared__ float smax[256];
    __shared__ int sidx[256];
    int tid = threadIdx.x;
    float best = -INFINITY;
    int bidx = 0x7fffffff;
    for (int i = tid; i < nblocks; i += 256) {
        float v = pmax[i];
        int ix = pidx[i];
        if (v > best || (v == best && ix < bidx)) { best = v; bidx = ix; }
    }
    smax[tid] = best;
    sidx[tid] = bidx;
    __syncthreads();
    for (int s = 128; s > 0; s >>= 1) {
        if (tid < s) {
            float v2 = smax[tid + s];
            int i2 = sidx[tid + s];
            if (v2 > smax[tid] || (v2 == smax[tid] && i2 < sidx[tid])) {
                smax[tid] = v2;
                sidx[tid] = i2;
            }
        }
        __syncthreads();
    }
    __shared__ float ht[F];
    if (tid < F) {
        float hv = h[(size_t)sidx[0] * F + tid] + b3[tid];
        ht[tid] = hv > 0.0f ? hv : 0.0f;
    }
    __syncthreads();
    if (tid < 2) {
        float acc = bt[tid];
#pragma unroll
        for (int k = 0; k < F; k++) acc += ht[k] * Wt[k * 2 + tid];
        out[2 * N_NODES + tid] = acc;
    } else if (tid < 11) {
        int j = tid - 2;
        float acc = bact[j];
#pragma unroll
        for (int k = 0; k < F; k++) acc += ht[k] * Wact[k * 9 + j];
        out[2 * N_NODES + 2 + j] = acc;
    }
}

extern "C" void kernel_launch(void* const* d_in, const int* in_sizes, int n_in,
                              void* d_out, int out_size, void* d_ws, size_t ws_size,
                              hipStream_t stream) {
    const float* x  = (const float*)d_in[0];
    const int*   ei = (const int*)d_in[1];
    const int E = in_sizes[1] / 2;
    const int* row = ei;
    const int* col = ei + E;
    const float* W1 = (const float*)d_in[2];
    const float* b1 = (const float*)d_in[3];
    const float* W2 = (const float*)d_in[4];
    const float* b2 = (const float*)d_in[5];
    const float* W3 = (const float*)d_in[6];
    const float* b3 = (const float*)d_in[7];
    const float* Wd = (const float*)d_in[8];
    const float* bd = (const float*)d_in[9];
    const float* Wa = (const float*)d_in[10];
    const float* ba = (const float*)d_in[11];
    const float* Wt = (const float*)d_in[12];
    const float* bt = (const float*)d_in[13];
    const float* Wact = (const float*)d_in[14];
    const float* bact = (const float*)d_in[15];

    float* out = (float*)d_out;
    float* ws  = (float*)d_ws;

    float* dis = ws;                                // N floats (deg then dis in-place)
    float* t   = ws + N_NODES;                      // N*F
    float* h   = t + (size_t)N_NODES * F;           // N*F
    float* pmax = h + (size_t)N_NODES * F;          // <=512
    int*   pidx = (int*)(pmax + 512);               // <=512

    const int B = 256;
    const int nblocks_heads = (N_NODES + B - 1) / B;

    // degree / dis
    hipMemsetAsync(dis, 0, (size_t)N_NODES * sizeof(float), stream);
    hipMemsetAsync(h, 0, (size_t)N_NODES * F * sizeof(float), stream);
    deg_kernel<<<(E + B - 1) / B, B, 0, stream>>>(col, dis, E);
    dis_kernel<<<(N_NODES + B - 1) / B, B, 0, stream>>>(dis, N_NODES);

    // layer 1
    transform1_kernel<<<((size_t)N_NODES * F + B - 1) / B, B, 0, stream>>>(x, W1, t, N_NODES);
    scatter_kernel<<<((size_t)E * 8 + B - 1) / B, B, 0, stream>>>(t, row, col, dis, h, E);

    // layer 2
    transform_relu_kernel<<<(N_NODES + 7) / 8, B, 0, stream>>>(h, b1, W2, t, N_NODES);
    hipMemsetAsync(h, 0, (size_t)N_NODES * F * sizeof(float), stream);
    scatter_kernel<<<((size_t)E * 8 + B - 1) / B, B, 0, stream>>>(t, row, col, dis, h, E);

    // layer 3
    transform_relu_kernel<<<(N_NODES + 7) / 8, B, 0, stream>>>(h, b2, W3, t, N_NODES);
    hipMemsetAsync(h, 0, (size_t)N_NODES * F * sizeof(float), stream);
    scatter_kernel<<<((size_t)E * 8 + B - 1) / B, B, 0, stream>>>(t, row, col, dis, h, E);

    // heads + argmax
    heads_kernel<<<nblocks_heads, B, 0, stream>>>(h, b3, Wd, bd, Wa, ba, out, pmax, pidx, N_NODES);
    final_kernel<<<1, B, 0, stream>>>(pmax, pidx, nblocks_heads, h, b3, Wt, bt, Wact, bact, out);
}

// Round 2
// 781.184 us; speedup vs baseline: 2.7988x; 2.7988x over previous
//
#include <hip/hip_runtime.h>
#include <math.h>

#define N_NODES 100000
#define F 32

// ---------------- degree count (int atomics, once) ----------------
__global__ void deg_kernel(const int* __restrict__ col, int* __restrict__ deg, int E) {
    int i = blockIdx.x * blockDim.x + threadIdx.x;
    if (i < E) atomicAdd(&deg[col[i]], 1);
}

// ---------------- single-block prefix scan: rowstart/cursor + dis ----------------
__global__ void scan_kernel(const int* __restrict__ deg, int* __restrict__ rowstart,
                            int* __restrict__ cursor, float* __restrict__ dis, int n) {
    __shared__ int ssum[1024];
    int tid = threadIdx.x;
    int chunk = (n + 1023) / 1024;
    int begin = tid * chunk;
    int end = begin + chunk; if (end > n) end = n;
    int s = 0;
    for (int i = begin; i < end; i++) s += deg[i];
    ssum[tid] = s;
    __syncthreads();
    for (int off = 1; off < 1024; off <<= 1) {
        int tmp = 0;
        if (tid >= off) tmp = ssum[tid - off];
        __syncthreads();
        if (tid >= off) ssum[tid] += tmp;
        __syncthreads();
    }
    int run = ssum[tid] - s;   // exclusive prefix of this thread's chunk
    for (int i = begin; i < end; i++) {
        rowstart[i] = run;
        cursor[i] = run;
        int d = deg[i];
        dis[i] = (d > 0) ? rsqrtf((float)d) : 0.0f;
        run += d;
    }
    if (tid == 1023) rowstart[n] = run;   // == E
}

// ---------------- CSR fill: group edges by target col ----------------
__global__ void fill_kernel(const int* __restrict__ row, const int* __restrict__ col,
                            int* __restrict__ cursor, int* __restrict__ csr_src, int E) {
    int e = blockIdx.x * blockDim.x + threadIdx.x;
    if (e < E) {
        int pos = atomicAdd(&cursor[col[e]], 1);
        csr_src[pos] = row[e];
    }
}

// ---------------- layer 1 transform: t = x @ W1 (x is N x 5) ----------------
__global__ void transform1_kernel(const float* __restrict__ x, const float* __restrict__ W,
                                  float* __restrict__ t, int n) {
    __shared__ float Ws[5 * F];
    int tid = threadIdx.x;
    if (tid < 5 * F) Ws[tid] = W[tid];
    __syncthreads();
    int gid = blockIdx.x * blockDim.x + tid;
    int node = gid >> 5;
    int f = gid & 31;
    if (node >= n) return;
    float acc = 0.0f;
#pragma unroll
    for (int k = 0; k < 5; k++) acc += x[node * 5 + k] * Ws[k * F + f];
    t[(size_t)node * F + f] = acc;
}

// ---------------- fused relu(h + b) @ W  (h is N x 32) ----------------
__global__ void transform_relu_kernel(const float* __restrict__ h, const float* __restrict__ b,
                                      const float* __restrict__ W, float* __restrict__ t, int n) {
    __shared__ float Ws[F * F];
    __shared__ float hs[256];
    int tid = threadIdx.x;
    for (int i = tid; i < F * F; i += 256) Ws[i] = W[i];
    int node = blockIdx.x * 8 + (tid >> 5);
    int f = tid & 31;
    float hv = 0.0f;
    if (node < n) hv = h[(size_t)node * F + f] + b[f];
    hs[tid] = hv > 0.0f ? hv : 0.0f;
    __syncthreads();
    if (node >= n) return;
    const float* hrow = &hs[(tid >> 5) << 5];
    float acc = 0.0f;
#pragma unroll
    for (int k = 0; k < F; k++) acc += hrow[k] * Ws[k * F + f];
    t[(size_t)node * F + f] = acc;
}

// ---------------- gather: h[v][f] = dis[v] * sum_{e: col=v} dis[row_e] * t[row_e][f] ----------------
// 32 threads per node (lane = feature), 8 nodes per 256-thread block.
__global__ void gather_kernel(const float* __restrict__ t, const int* __restrict__ rowstart,
                              const int* __restrict__ csr_src, const float* __restrict__ dis,
                              float* __restrict__ out, int n) {
    int tid = threadIdx.x;
    int node = blockIdx.x * 8 + (tid >> 5);
    if (node >= n) return;
    int f = tid & 31;
    int start = rowstart[node];
    int end = rowstart[node + 1];
    float acc0 = 0.0f, acc1 = 0.0f;
    int i = start;
    for (; i + 1 < end; i += 2) {
        int r0 = csr_src[i];
        int r1 = csr_src[i + 1];
        float d0 = dis[r0], d1 = dis[r1];
        acc0 += d0 * t[(size_t)r0 * F + f];
        acc1 += d1 * t[(size_t)r1 * F + f];
    }
    if (i < end) {
        int r = csr_src[i];
        acc0 += dis[r] * t[(size_t)r * F + f];
    }
    out[(size_t)node * F + f] = (acc0 + acc1) * dis[node];
}

// ---------------- heads: distance/attention per node + block argmax partials ----------------
__global__ void heads_kernel(const float* __restrict__ h, const float* __restrict__ b3,
                             const float* __restrict__ Wd, const float* __restrict__ bd,
                             const float* __restrict__ Wa, const float* __restrict__ ba,
                             float* __restrict__ out, float* __restrict__ pmax,
                             int* __restrict__ pidx, int n) {
    int tid = threadIdx.x;
    int node = blockIdx.x * blockDim.x + tid;
    float att = -INFINITY;
    int myidx = 0x7fffffff;
    if (node < n) {
        float dacc = 0.0f, aacc = 0.0f;
#pragma unroll
        for (int k = 0; k < F; k++) {
            float hv = h[(size_t)node * F + k] + b3[k];
            hv = hv > 0.0f ? hv : 0.0f;
            dacc += hv * Wd[k];
            aacc += hv * Wa[k];
        }
        dacc += bd[0];
        aacc += ba[0];
        out[node] = dacc;
        out[N_NODES + node] = aacc;
        att = aacc;
        myidx = node;
    }
    __shared__ float smax[256];
    __shared__ int sidx[256];
    smax[tid] = att;
    sidx[tid] = myidx;
    __syncthreads();
    for (int s = 128; s > 0; s >>= 1) {
        if (tid < s) {
            float v2 = smax[tid + s];
            int i2 = sidx[tid + s];
            if (v2 > smax[tid] || (v2 == smax[tid] && i2 < sidx[tid])) {
                smax[tid] = v2;
                sidx[tid] = i2;
            }
        }
        __syncthreads();
    }
    if (tid == 0) {
        pmax[blockIdx.x] = smax[0];
        pidx[blockIdx.x] = sidx[0];
    }
}

// ---------------- final: reduce partials, compute target head outputs ----------------
__global__ void final_kernel(const float* __restrict__ pmax, const int* __restrict__ pidx,
                             int nblocks, const float* __restrict__ h, const float* __restrict__ b3,
                             const float* __restrict__ Wt, const float* __restrict__ bt,
                             const float* __restrict__ Wact, const float* __restrict__ bact,
                             float* __restrict__ out) {
    __shared__ float smax[256];
    __shared__ int sidx[256];
    int tid = threadIdx.x;
    float best = -INFINITY;
    int bidx = 0x7fffffff;
    for (int i = tid; i < nblocks; i += 256) {
        float v = pmax[i];
        int ix = pidx[i];
        if (v > best || (v == best && ix < bidx)) { best = v; bidx = ix; }
    }
    smax[tid] = best;
    sidx[tid] = bidx;
    __syncthreads();
    for (int s = 128; s > 0; s >>= 1) {
        if (tid < s) {
            float v2 = smax[tid + s];
            int i2 = sidx[tid + s];
            if (v2 > smax[tid] || (v2 == smax[tid] && i2 < sidx[tid])) {
                smax[tid] = v2;
                sidx[tid] = i2;
            }
        }
        __syncthreads();
    }
    __shared__ float ht[F];
    if (tid < F) {
        float hv = h[(size_t)sidx[0] * F + tid] + b3[tid];
        ht[tid] = hv > 0.0f ? hv : 0.0f;
    }
    __syncthreads();
    if (tid < 2) {
        float acc = bt[tid];
#pragma unroll
        for (int k = 0; k < F; k++) acc += ht[k] * Wt[k * 2 + tid];
        out[2 * N_NODES + tid] = acc;
    } else if (tid < 11) {
        int j = tid - 2;
        float acc = bact[j];
#pragma unroll
        for (int k = 0; k < F; k++) acc += ht[k] * Wact[k * 9 + j];
        out[2 * N_NODES + 2 + j] = acc;
    }
}

extern "C" void kernel_launch(void* const* d_in, const int* in_sizes, int n_in,
                              void* d_out, int out_size, void* d_ws, size_t ws_size,
                              hipStream_t stream) {
    const float* x  = (const float*)d_in[0];
    const int*   ei = (const int*)d_in[1];
    const int E = in_sizes[1] / 2;
    const int* row = ei;
    const int* col = ei + E;
    const float* W1 = (const float*)d_in[2];
    const float* b1 = (const float*)d_in[3];
    const float* W2 = (const float*)d_in[4];
    const float* b2 = (const float*)d_in[5];
    const float* W3 = (const float*)d_in[6];
    const float* b3 = (const float*)d_in[7];
    const float* Wd = (const float*)d_in[8];
    const float* bd = (const float*)d_in[9];
    const float* Wa = (const float*)d_in[10];
    const float* ba = (const float*)d_in[11];
    const float* Wt = (const float*)d_in[12];
    const float* bt = (const float*)d_in[13];
    const float* Wact = (const float*)d_in[14];
    const float* bact = (const float*)d_in[15];

    float* out = (float*)d_out;
    float* ws  = (float*)d_ws;

    // workspace layout
    float* dis      = ws;                                  // N
    float* t        = ws + N_NODES;                        // N*F
    float* h        = t + (size_t)N_NODES * F;             // N*F
    int*   deg      = (int*)(h + (size_t)N_NODES * F);     // N
    int*   rowstart = deg + N_NODES;                       // N+1
    int*   cursor   = rowstart + N_NODES + 1;              // N
    int*   csr_src  = cursor + N_NODES;                    // E
    float* pmax     = (float*)(csr_src + E);               // <=512
    int*   pidx     = (int*)(pmax + 512);                  // <=512

    const int B = 256;
    const int nblocks_heads = (N_NODES + B - 1) / B;
    const int nblocks_nodes = (N_NODES + 7) / 8;

    // ---- build CSR (once per call, used 3x) ----
    hipMemsetAsync(deg, 0, (size_t)N_NODES * sizeof(int), stream);
    deg_kernel<<<(E + B - 1) / B, B, 0, stream>>>(col, deg, E);
    scan_kernel<<<1, 1024, 0, stream>>>(deg, rowstart, cursor, dis, N_NODES);
    fill_kernel<<<(E + B - 1) / B, B, 0, stream>>>(row, col, cursor, csr_src, E);

    // ---- layer 1 ----
    transform1_kernel<<<((size_t)N_NODES * F + B - 1) / B, B, 0, stream>>>(x, W1, t, N_NODES);
    gather_kernel<<<nblocks_nodes, B, 0, stream>>>(t, rowstart, csr_src, dis, h, N_NODES);

    // ---- layer 2 ----
    transform_relu_kernel<<<nblocks_nodes, B, 0, stream>>>(h, b1, W2, t, N_NODES);
    gather_kernel<<<nblocks_nodes, B, 0, stream>>>(t, rowstart, csr_src, dis, h, N_NODES);

    // ---- layer 3 ----
    transform_relu_kernel<<<nblocks_nodes, B, 0, stream>>>(h, b2, W3, t, N_NODES);
    gather_kernel<<<nblocks_nodes, B, 0, stream>>>(t, rowstart, csr_src, dis, h, N_NODES);

    // ---- heads + argmax ----
    heads_kernel<<<nblocks_heads, B, 0, stream>>>(h, b3, Wd, bd, Wa, ba, out, pmax, pidx, N_NODES);
    final_kernel<<<1, B, 0, stream>>>(pmax, pidx, nblocks_heads, h, b3, Wt, bt, Wact, bact, out);
}

// Round 3
// 474.981 us; speedup vs baseline: 4.6031x; 1.6447x over previous
//
#include <hip/hip_runtime.h>
#include <math.h>

#define N_NODES 100000
#define F 32

// ---------------- degree count (int atomics, once) ----------------
__global__ void deg_kernel(const int* __restrict__ col, int* __restrict__ deg, int E) {
    int i = blockIdx.x * blockDim.x + threadIdx.x;
    if (i < E) atomicAdd(&deg[col[i]], 1);
}

// ---------------- multi-block scan, step A: per-block sums ----------------
__global__ void reduce_blocks_kernel(const int* __restrict__ deg, int* __restrict__ bsum, int n) {
    __shared__ int sh[256];
    int tid = threadIdx.x;
    int gid = blockIdx.x * 256 + tid;
    sh[tid] = (gid < n) ? deg[gid] : 0;
    __syncthreads();
    for (int s = 128; s > 0; s >>= 1) {
        if (tid < s) sh[tid] += sh[tid + s];
        __syncthreads();
    }
    if (tid == 0) bsum[blockIdx.x] = sh[0];
}

// ---------------- step B: exclusive scan of block sums (nb <= 512) ----------------
__global__ void scan_bsum_kernel(const int* __restrict__ bsum, int* __restrict__ boff, int nb) {
    __shared__ int sh[512];
    int tid = threadIdx.x;
    int v = (tid < nb) ? bsum[tid] : 0;
    sh[tid] = v;
    __syncthreads();
    for (int off = 1; off < 512; off <<= 1) {
        int t2 = (tid >= off) ? sh[tid - off] : 0;
        __syncthreads();
        sh[tid] += t2;
        __syncthreads();
    }
    if (tid < nb) boff[tid] = sh[tid] - v;
}

// ---------------- step C: block-local scan + offset -> rowstart/cursor/dis ----------------
__global__ void scan_blocks_kernel(const int* __restrict__ deg, const int* __restrict__ boff,
                                   int* __restrict__ rowstart, int* __restrict__ cursor,
                                   float* __restrict__ dis, int n) {
    __shared__ int sh[256];
    int tid = threadIdx.x;
    int gid = blockIdx.x * 256 + tid;
    int v = (gid < n) ? deg[gid] : 0;
    sh[tid] = v;
    __syncthreads();
    for (int off = 1; off < 256; off <<= 1) {
        int t2 = (tid >= off) ? sh[tid - off] : 0;
        __syncthreads();
        sh[tid] += t2;
        __syncthreads();
    }
    int incl = sh[tid];
    int base = boff[blockIdx.x];
    if (gid < n) {
        int excl = base + incl - v;
        rowstart[gid] = excl;
        cursor[gid] = excl;
        dis[gid] = (v > 0) ? rsqrtf((float)v) : 0.0f;
        if (gid == n - 1) rowstart[n] = base + incl;
    }
}

// ---------------- CSR fill: group edges by target col ----------------
__global__ void fill_kernel(const int* __restrict__ row, const int* __restrict__ col,
                            int* __restrict__ cursor, int* __restrict__ csr_src, int E) {
    int e = blockIdx.x * blockDim.x + threadIdx.x;
    if (e < E) {
        int pos = atomicAdd(&cursor[col[e]], 1);
        csr_src[pos] = row[e];
    }
}

// ---------------- layer 1 transform: t = x @ W1 (x is N x 5) ----------------
__global__ void transform1_kernel(const float* __restrict__ x, const float* __restrict__ W,
                                  float* __restrict__ t, int n) {
    __shared__ float Ws[5 * F];
    int tid = threadIdx.x;
    if (tid < 5 * F) Ws[tid] = W[tid];
    __syncthreads();
    int gid = blockIdx.x * blockDim.x + tid;
    int node = gid >> 5;
    int f = gid & 31;
    if (node >= n) return;
    float acc = 0.0f;
#pragma unroll
    for (int k = 0; k < 5; k++) acc += x[node * 5 + k] * Ws[k * F + f];
    t[(size_t)node * F + f] = acc;
}

// ---------------- fused relu(h + b) @ W  (h is N x 32) ----------------
__global__ void transform_relu_kernel(const float* __restrict__ h, const float* __restrict__ b,
                                      const float* __restrict__ W, float* __restrict__ t, int n) {
    __shared__ float Ws[F * F];
    __shared__ float hs[256];
    int tid = threadIdx.x;
    for (int i = tid; i < F * F; i += 256) Ws[i] = W[i];
    int node = blockIdx.x * 8 + (tid >> 5);
    int f = tid & 31;
    float hv = 0.0f;
    if (node < n) hv = h[(size_t)node * F + f] + b[f];
    hs[tid] = hv > 0.0f ? hv : 0.0f;
    __syncthreads();
    if (node >= n) return;
    const float* hrow = &hs[(tid >> 5) << 5];
    float acc = 0.0f;
#pragma unroll
    for (int k = 0; k < F; k++) acc += hrow[k] * Ws[k * F + f];
    t[(size_t)node * F + f] = acc;
}

// ---------------- gather: h[v][f] = dis[v] * sum_{e: col=v} dis[row_e] * t[row_e][f] ----------------
// 32 threads per node (lane = feature), 8 nodes per 256-thread block.
__global__ void gather_kernel(const float* __restrict__ t, const int* __restrict__ rowstart,
                              const int* __restrict__ csr_src, const float* __restrict__ dis,
                              float* __restrict__ out, int n) {
    int tid = threadIdx.x;
    int node = blockIdx.x * 8 + (tid >> 5);
    if (node >= n) return;
    int f = tid & 31;
    int start = rowstart[node];
    int end = rowstart[node + 1];
    float acc0 = 0.0f, acc1 = 0.0f, acc2 = 0.0f, acc3 = 0.0f;
    int i = start;
    for (; i + 3 < end; i += 4) {
        int r0 = csr_src[i];
        int r1 = csr_src[i + 1];
        int r2 = csr_src[i + 2];
        int r3 = csr_src[i + 3];
        float d0 = dis[r0], d1 = dis[r1], d2 = dis[r2], d3 = dis[r3];
        acc0 += d0 * t[(size_t)r0 * F + f];
        acc1 += d1 * t[(size_t)r1 * F + f];
        acc2 += d2 * t[(size_t)r2 * F + f];
        acc3 += d3 * t[(size_t)r3 * F + f];
    }
    for (; i < end; i++) {
        int r = csr_src[i];
        acc0 += dis[r] * t[(size_t)r * F + f];
    }
    out[(size_t)node * F + f] = ((acc0 + acc1) + (acc2 + acc3)) * dis[node];
}

// ---------------- heads: distance/attention per node + block argmax partials ----------------
__global__ void heads_kernel(const float* __restrict__ h, const float* __restrict__ b3,
                             const float* __restrict__ Wd, const float* __restrict__ bd,
                             const float* __restrict__ Wa, const float* __restrict__ ba,
                             float* __restrict__ out, float* __restrict__ pmax,
                             int* __restrict__ pidx, int n) {
    int tid = threadIdx.x;
    int node = blockIdx.x * blockDim.x + tid;
    float att = -INFINITY;
    int myidx = 0x7fffffff;
    if (node < n) {
        float dacc = 0.0f, aacc = 0.0f;
#pragma unroll
        for (int k = 0; k < F; k++) {
            float hv = h[(size_t)node * F + k] + b3[k];
            hv = hv > 0.0f ? hv : 0.0f;
            dacc += hv * Wd[k];
            aacc += hv * Wa[k];
        }
        dacc += bd[0];
        aacc += ba[0];
        out[node] = dacc;
        out[N_NODES + node] = aacc;
        att = aacc;
        myidx = node;
    }
    __shared__ float smax[256];
    __shared__ int sidx[256];
    smax[tid] = att;
    sidx[tid] = myidx;
    __syncthreads();
    for (int s = 128; s > 0; s >>= 1) {
        if (tid < s) {
            float v2 = smax[tid + s];
            int i2 = sidx[tid + s];
            if (v2 > smax[tid] || (v2 == smax[tid] && i2 < sidx[tid])) {
                smax[tid] = v2;
                sidx[tid] = i2;
            }
        }
        __syncthreads();
    }
    if (tid == 0) {
        pmax[blockIdx.x] = smax[0];
        pidx[blockIdx.x] = sidx[0];
    }
}

// ---------------- final: reduce partials, compute target head outputs ----------------
__global__ void final_kernel(const float* __restrict__ pmax, const int* __restrict__ pidx,
                             int nblocks, const float* __restrict__ h, const float* __restrict__ b3,
                             const float* __restrict__ Wt, const float* __restrict__ bt,
                             const float* __restrict__ Wact, const float* __restrict__ bact,
                             float* __restrict__ out) {
    __shared__ float smax[256];
    __shared__ int sidx[256];
    int tid = threadIdx.x;
    float best = -INFINITY;
    int bidx = 0x7fffffff;
    for (int i = tid; i < nblocks; i += 256) {
        float v = pmax[i];
        int ix = pidx[i];
        if (v > best || (v == best && ix < bidx)) { best = v; bidx = ix; }
    }
    smax[tid] = best;
    sidx[tid] = bidx;
    __syncthreads();
    for (int s = 128; s > 0; s >>= 1) {
        if (tid < s) {
            float v2 = smax[tid + s];
            int i2 = sidx[tid + s];
            if (v2 > smax[tid] || (v2 == smax[tid] && i2 < sidx[tid])) {
                smax[tid] = v2;
                sidx[tid] = i2;
            }
        }
        __syncthreads();
    }
    __shared__ float ht[F];
    if (tid < F) {
        float hv = h[(size_t)sidx[0] * F + tid] + b3[tid];
        ht[tid] = hv > 0.0f ? hv : 0.0f;
    }
    __syncthreads();
    if (tid < 2) {
        float acc = bt[tid];
#pragma unroll
        for (int k = 0; k < F; k++) acc += ht[k] * Wt[k * 2 + tid];
        out[2 * N_NODES + tid] = acc;
    } else if (tid < 11) {
        int j = tid - 2;
        float acc = bact[j];
#pragma unroll
        for (int k = 0; k < F; k++) acc += ht[k] * Wact[k * 9 + j];
        out[2 * N_NODES + 2 + j] = acc;
    }
}

extern "C" void kernel_launch(void* const* d_in, const int* in_sizes, int n_in,
                              void* d_out, int out_size, void* d_ws, size_t ws_size,
                              hipStream_t stream) {
    const float* x  = (const float*)d_in[0];
    const int*   ei = (const int*)d_in[1];
    const int E = in_sizes[1] / 2;
    const int* row = ei;
    const int* col = ei + E;
    const float* W1 = (const float*)d_in[2];
    const float* b1 = (const float*)d_in[3];
    const float* W2 = (const float*)d_in[4];
    const float* b2 = (const float*)d_in[5];
    const float* W3 = (const float*)d_in[6];
    const float* b3 = (const float*)d_in[7];
    const float* Wd = (const float*)d_in[8];
    const float* bd = (const float*)d_in[9];
    const float* Wa = (const float*)d_in[10];
    const float* ba = (const float*)d_in[11];
    const float* Wt = (const float*)d_in[12];
    const float* bt = (const float*)d_in[13];
    const float* Wact = (const float*)d_in[14];
    const float* bact = (const float*)d_in[15];

    float* out = (float*)d_out;
    float* ws  = (float*)d_ws;

    // workspace layout
    float* dis      = ws;                                  // N
    float* t        = ws + N_NODES;                        // N*F
    float* h        = t + (size_t)N_NODES * F;             // N*F
    int*   deg      = (int*)(h + (size_t)N_NODES * F);     // N
    int*   rowstart = deg + N_NODES;                       // N+1
    int*   cursor   = rowstart + N_NODES + 1;              // N
    int*   csr_src  = cursor + N_NODES;                    // E
    float* pmax     = (float*)(csr_src + E);               // <=512
    int*   pidx     = (int*)(pmax + 512);                  // <=512
    int*   bsum     = pidx + 512;                          // <=512
    int*   boff     = bsum + 512;                          // <=512

    const int B = 256;
    const int nblocks_heads = (N_NODES + B - 1) / B;
    const int nblocks_nodes = (N_NODES + 7) / 8;
    const int nblocks_scan  = (N_NODES + 255) / 256;       // 391 <= 512

    // ---- build CSR (once per call, used 3x) ----
    hipMemsetAsync(deg, 0, (size_t)N_NODES * sizeof(int), stream);
    deg_kernel<<<(E + B - 1) / B, B, 0, stream>>>(col, deg, E);
    reduce_blocks_kernel<<<nblocks_scan, 256, 0, stream>>>(deg, bsum, N_NODES);
    scan_bsum_kernel<<<1, 512, 0, stream>>>(bsum, boff, nblocks_scan);
    scan_blocks_kernel<<<nblocks_scan, 256, 0, stream>>>(deg, boff, rowstart, cursor, dis, N_NODES);
    fill_kernel<<<(E + B - 1) / B, B, 0, stream>>>(row, col, cursor, csr_src, E);

    // ---- layer 1 ----
    transform1_kernel<<<((size_t)N_NODES * F + B - 1) / B, B, 0, stream>>>(x, W1, t, N_NODES);
    gather_kernel<<<nblocks_nodes, B, 0, stream>>>(t, rowstart, csr_src, dis, h, N_NODES);

    // ---- layer 2 ----
    transform_relu_kernel<<<nblocks_nodes, B, 0, stream>>>(h, b1, W2, t, N_NODES);
    gather_kernel<<<nblocks_nodes, B, 0, stream>>>(t, rowstart, csr_src, dis, h, N_NODES);

    // ---- layer 3 ----
    transform_relu_kernel<<<nblocks_nodes, B, 0, stream>>>(h, b2, W3, t, N_NODES);
    gather_kernel<<<nblocks_nodes, B, 0, stream>>>(t, rowstart, csr_src, dis, h, N_NODES);

    // ---- heads + argmax ----
    heads_kernel<<<nblocks_heads, B, 0, stream>>>(h, b3, Wd, bd, Wa, ba, out, pmax, pidx, N_NODES);
    final_kernel<<<1, B, 0, stream>>>(pmax, pidx, nblocks_heads, h, b3, Wt, bt, Wact, bact, out);
}